// Round 6
// baseline (144.794 us; speedup 1.0000x reference)
//
#include <hip/hip_runtime.h>
#include <hip/hip_bf16.h>
#include <stdint.h>

// Problem constants
#define NB   8
#define KL   512
#define QD   16
#define SD   128
#define ED   256
#define RPN  (QD*SD)   // 2048 rows (q,s) per n
#define BMR  64        // query rows per fused-attention block
#define FRAG 512       // elements per B-fragment (64 lanes x 8 bf16)
#define PAN  131072    // elements per n-panel of a fragment buffer (256 frags)

typedef __hip_bfloat16 bf16;
using s16x8 = __attribute__((ext_vector_type(8))) short;  // 8 bf16 = 4 VGPRs
using f32x4 = __attribute__((ext_vector_type(4))) float;  // MFMA accumulator

__device__ __forceinline__ float b2f(unsigned short u){
    union { uint32_t i; float f; } v; v.i = ((uint32_t)u) << 16; return v.f;
}
__device__ __forceinline__ float b2f_hi(uint32_t u){
    union { uint32_t i; float f; } v; v.i = u & 0xFFFF0000u; return v.f;
}
__device__ __forceinline__ float b2f_lo(uint32_t u){
    union { uint32_t i; float f; } v; v.i = u << 16; return v.f;
}
__device__ __forceinline__ unsigned short f2b(float f){
    union { float ff; uint32_t i; } v; v.ff = f;
    uint32_t lsb = (v.i >> 16) & 1;
    v.i += 0x7FFFu + lsb;               // RNE
    return (unsigned short)(v.i >> 16);
}
__device__ __forceinline__ uint32_t cvtpk(float lo, float hi){
    uint32_t r;
    asm("v_cvt_pk_bf16_f32 %0, %1, %2" : "=v"(r) : "v"(lo), "v"(hi));
    return r;
}
__device__ __forceinline__ f32x4 mfma16(s16x8 a, s16x8 b, f32x4 c){
    return __builtin_amdgcn_mfma_f32_16x16x32_bf16(a, b, c, 0, 0, 0);
}

template<bool B>
__device__ __forceinline__ float ldin(const void* p, size_t i){
    if (B) return b2f(((const unsigned short*)p)[i]);
    else   return ((const float*)p)[i];
}

// ---------------- inline dtype probe ----------------
__device__ bool probe_bf16(const uint32_t* __restrict__ w, int* pc){
    if (threadIdx.x == 0) *pc = 0;
    __syncthreads();
    if (threadIdx.x < 256){
        int local = 0;
        #pragma unroll
        for (int i = 0; i < 4; ++i){
            uint32_t x = w[threadIdx.x*4 + i];
            uint32_t e = (x >> 7) & 0xFFu;
            local += (e >= 120u && e <= 132u) ? 1 : 0;
        }
        if (local) atomicAdd(pc, local);
    }
    __syncthreads();
    return *pc > 512;
}

// W-plane fragment address for the proj GEMM (B-operand, K=256 inner dim i,
// output col o): frag fW = (o>>4)*8 + (i>>5); lane = (o&15)|(((i>>3)&3)<<4);
// elem = i&7.  addr = fW*512 + lane*8 + elem.
__device__ __forceinline__ int waddr(int i, int o){
    return (((o >> 4)*8 + (i >> 5)) << 9) + (((o & 15) | (((i >> 3) & 3) << 4)) << 3) + (i & 7);
}

// ---------------- prep: Gt planes (blocks 0-255) + Mt planes (256-287) ------
template<bool B>
__device__ void gt_body(const void* __restrict__ Wq, const void* __restrict__ Wk,
                        unsigned short* __restrict__ WgH,
                        unsigned short* __restrict__ WgL, int bx){
    int b = bx, a = threadIdx.x;       // i = b (k-dim), o = a (out col)
    float s = 0.f;
    #pragma unroll 8
    for (int d = 0; d < 256; ++d)
        s += ldin<B>(Wq, (size_t)d*256 + a) * ldin<B>(Wk, (size_t)d*256 + b);
    unsigned short hi = f2b(s);
    unsigned short lo = f2b(s - b2f(hi));
    int ad = waddr(b, a);
    WgH[ad] = hi; WgL[ad] = lo;
}
template<bool B>
__device__ void wosmt_body(const void* __restrict__ Wo, const void* __restrict__ Wv,
                           unsigned short* __restrict__ WmH,
                           unsigned short* __restrict__ WmL, int bx, float (*sm)[256]){
    int t = threadIdx.x, e0 = bx*8;
    #pragma unroll
    for (int je = 0; je < 8; ++je){
        int e = e0 + je;
        float s = 0.f;
        #pragma unroll
        for (int h = 0; h < 8; ++h) s += ldin<B>(Wo, (size_t)e*2048 + h*256 + t);
        sm[je][t] = s;
    }
    __syncthreads();
    float acc[8] = {0,0,0,0,0,0,0,0};
    #pragma unroll 4
    for (int dp = 0; dp < 256; ++dp){
        float wv = ldin<B>(Wv, (size_t)dp*256 + t);
        #pragma unroll
        for (int je = 0; je < 8; ++je) acc[je] += sm[je][dp] * wv;
    }
    #pragma unroll
    for (int je = 0; je < 8; ++je){
        unsigned short hi = f2b(acc[je]);
        unsigned short lo = f2b(acc[je] - b2f(hi));
        int ad = waddr(t, e0 + je);
        WmH[ad] = hi; WmL[ad] = lo;
    }
}
__global__ __launch_bounds__(256)
void k_prep(const void* __restrict__ values,
            const void* __restrict__ Wq, const void* __restrict__ Wk,
            const void* __restrict__ Wo, const void* __restrict__ Wv,
            unsigned short* __restrict__ WgH, unsigned short* __restrict__ WgL,
            unsigned short* __restrict__ WmH, unsigned short* __restrict__ WmL){
    __shared__ float sm[8][256];
    __shared__ int pc;
    bool bf = probe_bf16((const uint32_t*)values, &pc);
    if (blockIdx.x < 256){
        if (bf) gt_body<true >(Wq, Wk, WgH, WgL, blockIdx.x);
        else    gt_body<false>(Wq, Wk, WgH, WgL, blockIdx.x);
    } else {
        int bx = blockIdx.x - 256;
        if (bf) wosmt_body<true >(Wo, Wv, WmH, WmL, bx, sm);
        else    wosmt_body<false>(Wo, Wv, WmH, WmL, bx, sm);
    }
}

// ---------------- MFMA projections -> frag-order kkF / utF ------------------
// 32 rows/block (halves W-plane L2 traffic vs 16): 128 key-blocks + 128
// value-blocks. f32 A split to bf16 hi/lo in-register, 3 MFMA passes.
// D -> 16KB LDS staging in frag-image order -> linear dwordx4 copyout.
template<bool B>
__device__ void projM_body(const void* __restrict__ A,
                           const unsigned short* __restrict__ WH,
                           const unsigned short* __restrict__ WL,
                           unsigned short* __restrict__ outF,
                           int bx, bool keysHalf, unsigned short* St){
    int t = threadIdx.x, lane = t & 63, w = t >> 6;
    int l15 = t & 15, g = (t >> 4) & 3;
    int n   = bx >> 4;
    int r0n = (bx & 15) * 32;
    int r0  = n*512 + r0n;              // row in the 4096-row matrix

    f32x4 acc[2][2];
    #pragma unroll
    for (int rt = 0; rt < 2; ++rt)
        #pragma unroll
        for (int c = 0; c < 2; ++c) acc[rt][c] = (f32x4){0.f,0.f,0.f,0.f};

    s16x8 wh[3][2], wl[3][2];
    auto LDW = [&](int ks, int sl){
        #pragma unroll
        for (int c = 0; c < 2; ++c){
            size_t off = (size_t)(((w*2 + c)*8 + ks)*512 + lane*8);
            wh[sl][c] = *(const s16x8*)(WH + off);
            wl[sl][c] = *(const s16x8*)(WL + off);
        }
    };
    float4 ar[2][2][2];                 // [slot][rt][half] raw f32
    s16x8  ab[2][2];                    // [slot][rt] bf16 direct
    auto LDA = [&](int ks, int sl){
        #pragma unroll
        for (int rt = 0; rt < 2; ++rt){
            size_t idx = (size_t)(r0 + rt*16 + l15)*256 + ks*32 + g*8;
            if (B) ab[sl][rt] = *(const s16x8*)((const unsigned short*)A + idx);
            else { ar[sl][rt][0] = *(const float4*)((const float*)A + idx);
                   ar[sl][rt][1] = *(const float4*)((const float*)A + idx + 4); }
        }
    };
    LDW(0,0); LDW(1,1); LDA(0,0); LDA(1,1);

    #pragma unroll
    for (int ks = 0; ks < 8; ++ks){
        int s = ks & 1, sw = ks % 3;
        s16x8 ah[2], al[2];
        #pragma unroll
        for (int rt = 0; rt < 2; ++rt){
            if (B){
                ah[rt] = ab[s][rt];
            } else {
                union { s16x8 v; uint32_t u[4]; } H, L;
                float4 x0 = ar[s][rt][0], x1 = ar[s][rt][1];
                H.u[0] = cvtpk(x0.x, x0.y); H.u[1] = cvtpk(x0.z, x0.w);
                H.u[2] = cvtpk(x1.x, x1.y); H.u[3] = cvtpk(x1.z, x1.w);
                L.u[0] = cvtpk(x0.x - b2f_lo(H.u[0]), x0.y - b2f_hi(H.u[0]));
                L.u[1] = cvtpk(x0.z - b2f_lo(H.u[1]), x0.w - b2f_hi(H.u[1]));
                L.u[2] = cvtpk(x1.x - b2f_lo(H.u[2]), x1.y - b2f_hi(H.u[2]));
                L.u[3] = cvtpk(x1.z - b2f_lo(H.u[3]), x1.w - b2f_hi(H.u[3]));
                ah[rt] = H.v; al[rt] = L.v;
            }
        }
        if (ks + 2 < 8) LDA(ks + 2, s);     // slot just consumed
        #pragma unroll
        for (int rt = 0; rt < 2; ++rt)
            #pragma unroll
            for (int c = 0; c < 2; ++c){
                acc[rt][c] = mfma16(ah[rt], wh[sw][c], acc[rt][c]);
                if (!B) acc[rt][c] = mfma16(al[rt], wh[sw][c], acc[rt][c]);
                acc[rt][c] = mfma16(ah[rt], wl[sw][c], acc[rt][c]);
            }
        if (ks + 2 < 8) LDW(ks + 2, (ks + 2) % 3);
    }

    // D scatter to St in frag-image order.
    #pragma unroll
    for (int rt = 0; rt < 2; ++rt){
        #pragma unroll
        for (int c = 0; c < 2; ++c){
            #pragma unroll
            for (int j = 0; j < 4; ++j){
                int rloc = g*4 + j;              // 0..15 within rt-tile
                int col  = (w*2 + c)*16 + l15;
                int idx;
                if (keysHalf)
                    // kkF frag(K16=(r0n>>4)+rt, ks_e=col>>5); slab rt = 8 frags.
                    idx = rt*4096 + ((col >> 5) << 9)
                        + ((rloc | (((col >> 3) & 3) << 4)) << 3) + (col & 7);
                else {
                    // utF frag(E16=col>>4, ks2=r0n>>5) -- block = full ks2 group.
                    int kl = rt*16 + rloc;       // key local 0..31
                    idx = ((col >> 4) << 9)
                        + (((col & 15) | ((kl >> 3) << 4)) << 3) + (kl & 7);
                }
                St[idx] = f2b(acc[rt][c][j]);
            }
        }
    }
    __syncthreads();

    // copyout: 8192 elems = 512 thr x 16 (two dwordx4 each)
    #pragma unroll
    for (int h = 0; h < 2; ++h){
        int s8 = t*8 + h*4096;
        if (keysHalf){
            size_t base = (size_t)n*PAN + (size_t)((r0n >> 4)*8)*512;
            *(s16x8*)(outF + base + s8) = *(const s16x8*)(St + s8);
        } else {
            int ks2 = r0n >> 5;
            int fl = s8 >> 9, off = s8 & 511;
            *(s16x8*)(outF + (size_t)n*PAN + (size_t)((fl*16 + ks2)*512 + off))
                = *(const s16x8*)(St + s8);
        }
    }
}
__global__ __launch_bounds__(512)
void k_projM(const void* __restrict__ keys, const void* __restrict__ values,
             const unsigned short* __restrict__ WgH, const unsigned short* __restrict__ WgL,
             const unsigned short* __restrict__ WmH, const unsigned short* __restrict__ WmL,
             unsigned short* __restrict__ kkF, unsigned short* __restrict__ utF){
    __shared__ unsigned short St[8192];   // 16 KB staging
    __shared__ int pc;
    bool bf = probe_bf16((const uint32_t*)values, &pc);
    int bx = blockIdx.x;
    bool keysHalf = (bx < 128);
    int bxl = bx & 127;
    if (keysHalf){
        if (bf) projM_body<true >(keys, WgH, WgL, kkF, bxl, true, St);
        else    projM_body<false>(keys, WgH, WgL, kkF, bxl, true, St);
    } else {
        if (bf) projM_body<true >(values, WmH, WmL, utF, bxl, false, St);
        else    projM_body<false>(values, WmH, WmL, utF, bxl, false, St);
    }
}

// ---------------- fused: MFMA QK^T -> in-reg softmax -> MFMA PV -> +bo -------
// BMR=64: 256 blocks (32 q-tiles x 8 n), 512 thr / 8 waves, 1 block/CU
// (LDS ~100 KB), exactly one grid round; n=bid&7 pins each n to one XCD.
// Halves kk/ut panel L2 traffic vs BMR=32 (32 blocks/n instead of 64).
// GEMM1: wave w owns keys [w*64,+64) x 4 row-tiles: acc1[4][4], 128 MFMA.
// Softmax runs IN PLACE on acc1 (no extra p[] regs).
// GEMM2: wave w owns e-tiles {2w,2w+1} x 4 row-tiles: acc2[4][2], 128 MFMA.
template<bool B>
__device__ void fused_body(const void* __restrict__ query,
                           const unsigned short* __restrict__ kkF,
                           const unsigned short* __restrict__ utF,
                           const int* __restrict__ mask,
                           const void* __restrict__ bo,
                           void* __restrict__ out,
                           unsigned short* Qs, unsigned short* Pf,
                           float* redM, float* redS){
    int bid = blockIdx.x;
    int n   = bid & 7;
    int r0  = (bid >> 3) * BMR;
    int t   = threadIdx.x;
    int l15 = t & 15;
    int g   = (t >> 4) & 3;            // 16-lane group within wave
    int w   = t >> 6;                  // wave 0..7
    int lane = t & 63;

    const unsigned short* Kn = kkF + (size_t)n*PAN;
    const unsigned short* Un = utF + (size_t)n*PAN;
    const int* mn = mask + n*KL;

    // ---- phase 0: stage Q tile (64 rows) to LDS as bf16, XOR-swizzled ----
    #pragma unroll
    for (int rr = 0; rr < 2; ++rr){
        int row = rr*32 + (t >> 4);    // 0..63
        int c0  = (t & 15) * 16;
        int sw  = (row & 7) << 3;      // 8-elem (16B) granularity
        size_t qoff = (size_t)n*RPN*ED + (size_t)(r0 + row)*ED + c0;
        if (B){
            const unsigned short* qp = (const unsigned short*)query + qoff;
            s16x8 v0 = *(const s16x8*)(qp);
            s16x8 v1 = *(const s16x8*)(qp + 8);
            *(s16x8*)&Qs[(row*ED + c0    ) ^ sw] = v0;
            *(s16x8*)&Qs[(row*ED + c0 + 8) ^ sw] = v1;
        } else {
            const float* qp = (const float*)query + qoff;
            float4 x0 = *(const float4*)(qp);
            float4 x1 = *(const float4*)(qp + 4);
            float4 x2 = *(const float4*)(qp + 8);
            float4 x3 = *(const float4*)(qp + 12);
            union { s16x8 v; uint32_t u[4]; } pk;
            pk.u[0] = cvtpk(x0.x,x0.y); pk.u[1] = cvtpk(x0.z,x0.w);
            pk.u[2] = cvtpk(x1.x,x1.y); pk.u[3] = cvtpk(x1.z,x1.w);
            *(s16x8*)&Qs[(row*ED + c0    ) ^ sw] = pk.v;
            pk.u[0] = cvtpk(x2.x,x2.y); pk.u[1] = cvtpk(x2.z,x2.w);
            pk.u[2] = cvtpk(x3.x,x3.y); pk.u[3] = cvtpk(x3.z,x3.w);
            *(s16x8*)&Qs[(row*ED + c0 + 8) ^ sw] = pk.v;
        }
    }
    __syncthreads();

    int asw = (l15 & 7) << 3;

    // ---- GEMM1: S[row=rt*16+g*4+j][key=w*64+c*16+l15] in acc1 ----
    f32x4 acc1[4][4];
    {
        #pragma unroll
        for (int rt = 0; rt < 4; ++rt)
            #pragma unroll
            for (int c = 0; c < 4; ++c) acc1[rt][c] = (f32x4){0.f,0.f,0.f,0.f};

        const unsigned short* kb = Kn + (size_t)w*16384 + (size_t)lane*8;
        s16x8 bb[3][4];                // rotating buffer, 2 k-steps ahead
        auto LDK = [&](int KS, int SL){
            #pragma unroll
            for (int c = 0; c < 4; ++c)
                bb[SL][c] = *(const s16x8*)(kb + (size_t)(c*8 + KS)*FRAG);
        };
        LDK(0,0); LDK(1,1);
        #pragma unroll
        for (int ks = 0; ks < 8; ++ks){
            if (ks + 2 < 8) LDK(ks + 2, (ks + 2) % 3);
            int col = ks*32 + g*8;
            #pragma unroll
            for (int rt = 0; rt < 4; ++rt){
                s16x8 a = *(const s16x8*)&Qs[((rt*16 + l15)*ED + col) ^ asw];
                #pragma unroll
                for (int c = 0; c < 4; ++c)
                    acc1[rt][c] = mfma16(a, bb[ks % 3][c], acc1[rt][c]);
            }
        }
        // mask + scale in place
        #pragma unroll
        for (int c = 0; c < 4; ++c){
            bool zz = (mn[w*64 + c*16 + l15] == 0);
            #pragma unroll
            for (int rt = 0; rt < 4; ++rt)
                #pragma unroll
                for (int j = 0; j < 4; ++j)
                    acc1[rt][c][j] = zz ? -1e20f : acc1[rt][c][j] * 0.0625f;
        }
    }

    // ---- softmax in place: wave-local reduce + cross-wave via 4KB LDS ----
    {
        #pragma unroll
        for (int rt = 0; rt < 4; ++rt)
            #pragma unroll
            for (int j = 0; j < 4; ++j){
                float m0 = fmaxf(fmaxf(acc1[rt][0][j], acc1[rt][1][j]),
                                 fmaxf(acc1[rt][2][j], acc1[rt][3][j]));
                #pragma unroll
                for (int off = 1; off < 16; off <<= 1)
                    m0 = fmaxf(m0, __shfl_xor(m0, off, 16));
                if (l15 == 0) redM[(rt*16 + g*4 + j)*8 + w] = m0;
            }
        __syncthreads();
        #pragma unroll
        for (int rt = 0; rt < 4; ++rt)
            #pragma unroll
            for (int j = 0; j < 4; ++j){
                int row = rt*16 + g*4 + j;
                float4 a = *(const float4*)&redM[row*8];
                float4 b = *(const float4*)&redM[row*8 + 4];
                float m = fmaxf(fmaxf(fmaxf(a.x,a.y),fmaxf(a.z,a.w)),
                                fmaxf(fmaxf(b.x,b.y),fmaxf(b.z,b.w)));
                float s = 0.f;
                #pragma unroll
                for (int c = 0; c < 4; ++c){
                    acc1[rt][c][j] = __expf(acc1[rt][c][j] - m);
                    s += acc1[rt][c][j];
                }
                #pragma unroll
                for (int off = 1; off < 16; off <<= 1)
                    s += __shfl_xor(s, off, 16);
                if (l15 == 0) redS[row*8 + w] = s;
            }
        __syncthreads();
        // normalize + write P in A-fragment order: frag(rt, ks=w*2+(c>>1));
        // lane = (g*4+j) | (((c&1)*2 + (l15>>3))<<4); elem = l15&7.
        int ihi = ((l15 >> 3) << 4);
        int ilo = l15 & 7;
        #pragma unroll
        for (int rt = 0; rt < 4; ++rt){
            #pragma unroll
            for (int j = 0; j < 4; ++j){
                int row = rt*16 + g*4 + j;
                float4 a = *(const float4*)&redS[row*8];
                float4 b = *(const float4*)&redS[row*8 + 4];
                float inv = 1.0f / ((a.x+a.y+a.z+a.w) + (b.x+b.y+b.z+b.w));
                #pragma unroll
                for (int c = 0; c < 4; ++c){
                    int lp = (g*4 + j) | (((c & 1) << 5) | ihi);
                    int elem = (rt*16 + w*2 + (c >> 1))*FRAG + lp*8 + ilo;
                    Pf[elem] = f2b(acc1[rt][c][j] * inv);
                }
            }
        }
    }
    __syncthreads();

    // ---- GEMM2: Out[64 x 2 e-tiles] = P . u ----
    {
        f32x4 acc2[4][2];
        #pragma unroll
        for (int rt = 0; rt < 4; ++rt)
            #pragma unroll
            for (int c = 0; c < 2; ++c) acc2[rt][c] = (f32x4){0.f,0.f,0.f,0.f};

        const unsigned short* ub = Un + (size_t)(2*w)*8192 + (size_t)lane*8;
        s16x8 bu[3][2];
        auto LDU = [&](int KS, int SL){
            #pragma unroll
            for (int c = 0; c < 2; ++c)
                bu[SL][c] = *(const s16x8*)(ub + (size_t)(c*16 + KS)*FRAG);
        };
        LDU(0,0); LDU(1,1);
        #pragma unroll
        for (int ks = 0; ks < 16; ++ks){
            if (ks + 2 < 16) LDU(ks + 2, (ks + 2) % 3);
            #pragma unroll
            for (int rt = 0; rt < 4; ++rt){
                s16x8 p = *(const s16x8*)&Pf[(rt*16 + ks)*FRAG + lane*8];
                #pragma unroll
                for (int c = 0; c < 2; ++c)
                    acc2[rt][c] = mfma16(p, bu[ks % 3][c], acc2[rt][c]);
            }
        }
        float bov[2];
        #pragma unroll
        for (int c = 0; c < 2; ++c) bov[c] = ldin<B>(bo, (2*w + c)*16 + l15);
        #pragma unroll
        for (int rt = 0; rt < 4; ++rt){
            #pragma unroll
            for (int j = 0; j < 4; ++j){
                int row = rt*16 + g*4 + j;
                #pragma unroll
                for (int c = 0; c < 2; ++c){
                    int e = (2*w + c)*16 + l15;
                    float val = acc2[rt][c][j] + bov[c];
                    size_t oidx = (size_t)n*RPN*ED + (size_t)(r0 + row)*ED + e;
                    if (B) ((unsigned short*)out)[oidx] = f2b(val);
                    else   ((float*)out)[oidx] = val;
                }
            }
        }
    }
}

__global__ __launch_bounds__(512, 2)
void k_fused5(const void* __restrict__ values, const void* __restrict__ query,
              const unsigned short* __restrict__ kkF,
              const unsigned short* __restrict__ utF,
              const int* __restrict__ mask, const void* __restrict__ bo,
              void* __restrict__ out){
    __shared__ unsigned short Qs[BMR*ED];   // 32 KB
    __shared__ unsigned short Pf[64*FRAG];  // 64 KB (A-frag-order P)
    __shared__ float redM[BMR*8];           // 2 KB
    __shared__ float redS[BMR*8];           // 2 KB   (total ~100 KB -> 1 blk/CU)
    __shared__ int pc;
    bool bf = probe_bf16((const uint32_t*)values, &pc);
    if (bf) fused_body<true >(query, kkF, utF, mask, bo, out, Qs, Pf, redM, redS);
    else    fused_body<false>(query, kkF, utF, mask, bo, out, Qs, Pf, redM, redS);
}

// ---------------- launch ----------------
extern "C" void kernel_launch(void* const* d_in, const int* in_sizes, int n_in,
                              void* d_out, int out_size, void* d_ws, size_t ws_size,
                              hipStream_t stream){
    const void* values = d_in[0];
    const void* keys   = d_in[1];
    const void* query  = d_in[2];
    const int*  mask   = (const int*)d_in[3];
    const void* Wv     = d_in[4];
    const void* Wk     = d_in[5];
    const void* Wq     = d_in[6];
    const void* Wo     = d_in[7];
    const void* bo     = d_in[8];

    // ws layout (u16 elems): [WgH 64Ki][WgL 64Ki][WmH 64Ki][WmL 64Ki]
    //                        [kkF 1Mi][utF 1Mi]
    unsigned short* wsu = (unsigned short*)d_ws;
    unsigned short* wgh = wsu;
    unsigned short* wgl = wsu + 65536;
    unsigned short* wmh = wsu + 131072;
    unsigned short* wml = wsu + 196608;
    unsigned short* ws_kk = wsu + 262144;
    unsigned short* ws_u  = ws_kk + (size_t)NB*PAN;

    k_prep  <<< 288, 256, 0, stream>>>(values, Wq, Wk, Wo, Wv, wgh, wgl, wmh, wml);
    k_projM <<< 256, 512, 0, stream>>>(keys, values, wgh, wgl, wmh, wml, ws_kk, ws_u);
    k_fused5<<< 256, 512, 0, stream>>>(values, query, ws_kk, ws_u, mask, bo, d_out);
}

// Round 7
// 136.834 us; speedup vs baseline: 1.0582x; 1.0582x over previous
//
#include <hip/hip_runtime.h>
#include <hip/hip_bf16.h>
#include <stdint.h>

// Problem constants
#define NB   8
#define KL   512
#define QD   16
#define SD   128
#define ED   256
#define RPN  (QD*SD)   // 2048 rows (q,s) per n
#define BMR  32        // query rows per fused-attention block
#define FRAG 512       // elements per B-fragment (64 lanes x 8 bf16)
#define PAN  131072    // elements per n-panel of a fragment buffer (256 frags)

typedef __hip_bfloat16 bf16;
using s16x8 = __attribute__((ext_vector_type(8))) short;  // 8 bf16 = 4 VGPRs
using f32x4 = __attribute__((ext_vector_type(4))) float;  // MFMA accumulator

__device__ __forceinline__ float b2f(unsigned short u){
    union { uint32_t i; float f; } v; v.i = ((uint32_t)u) << 16; return v.f;
}
__device__ __forceinline__ float b2f_hi(uint32_t u){
    union { uint32_t i; float f; } v; v.i = u & 0xFFFF0000u; return v.f;
}
__device__ __forceinline__ float b2f_lo(uint32_t u){
    union { uint32_t i; float f; } v; v.i = u << 16; return v.f;
}
__device__ __forceinline__ unsigned short f2b(float f){
    union { float ff; uint32_t i; } v; v.ff = f;
    uint32_t lsb = (v.i >> 16) & 1;
    v.i += 0x7FFFu + lsb;               // RNE
    return (unsigned short)(v.i >> 16);
}
__device__ __forceinline__ uint32_t cvtpk(float lo, float hi){
    uint32_t r;
    asm("v_cvt_pk_bf16_f32 %0, %1, %2" : "=v"(r) : "v"(lo), "v"(hi));
    return r;
}
__device__ __forceinline__ f32x4 mfma16(s16x8 a, s16x8 b, f32x4 c){
    return __builtin_amdgcn_mfma_f32_16x16x32_bf16(a, b, c, 0, 0, 0);
}

template<bool B>
__device__ __forceinline__ float ldin(const void* p, size_t i){
    if (B) return b2f(((const unsigned short*)p)[i]);
    else   return ((const float*)p)[i];
}

// ---------------- inline dtype probe ----------------
__device__ bool probe_bf16(const uint32_t* __restrict__ w, int* pc){
    if (threadIdx.x == 0) *pc = 0;
    __syncthreads();
    if (threadIdx.x < 256){
        int local = 0;
        #pragma unroll
        for (int i = 0; i < 4; ++i){
            uint32_t x = w[threadIdx.x*4 + i];
            uint32_t e = (x >> 7) & 0xFFu;
            local += (e >= 120u && e <= 132u) ? 1 : 0;
        }
        if (local) atomicAdd(pc, local);
    }
    __syncthreads();
    return *pc > 512;
}

// W-plane fragment address for the proj GEMM (B-operand, K=256 inner dim i,
// output col o): frag fW = (o>>4)*8 + (i>>5); lane = (o&15)|(((i>>3)&3)<<4);
// elem = i&7.  addr = fW*512 + lane*8 + elem.
__device__ __forceinline__ int waddr(int i, int o){
    return (((o >> 4)*8 + (i >> 5)) << 9) + (((o & 15) | (((i >> 3) & 3) << 4)) << 3) + (i & 7);
}

// ---------------- prep: Gt planes (blocks 0-255) + Mt planes (256-287) ------
// 512 threads/block; the 256-deep serial k-loops are SPLIT-D across two
// thread halves (halves the dependent-load chain at 1 wave/SIMD occupancy),
// partials combined via LDS.
template<bool B>
__device__ void gt_body(const void* __restrict__ Wq, const void* __restrict__ Wk,
                        unsigned short* __restrict__ WgH,
                        unsigned short* __restrict__ WgL, int bx,
                        float (*ps)[2048]){
    int t = threadIdx.x;
    int a = t & 255, hf = t >> 8;
    int b = bx;
    int d0 = hf * 128;
    float s = 0.f;
    #pragma unroll 8
    for (int d = d0; d < d0 + 128; ++d)
        s += ldin<B>(Wq, (size_t)d*256 + a) * ldin<B>(Wk, (size_t)d*256 + b);
    ps[hf][a] = s;
    __syncthreads();
    if (t < 256){
        float v = ps[0][t] + ps[1][t];
        unsigned short hi = f2b(v);
        unsigned short lo = f2b(v - b2f(hi));
        int ad = waddr(b, t);
        WgH[ad] = hi; WgL[ad] = lo;
    }
}
template<bool B>
__device__ void wosmt_body(const void* __restrict__ Wo, const void* __restrict__ Wv,
                           unsigned short* __restrict__ WmH,
                           unsigned short* __restrict__ WmL, int bx,
                           float (*sm)[256], float (*ps)[2048]){
    int t = threadIdx.x, d = t & 255, hf = t >> 8, e0 = bx*8;
    // phase 1: wos rows; thread-half owns 4 of the 8 e-rows
    #pragma unroll
    for (int jj = 0; jj < 4; ++jj){
        int je = hf*4 + jj;
        int e  = e0 + je;
        float s = 0.f;
        #pragma unroll
        for (int h = 0; h < 8; ++h) s += ldin<B>(Wo, (size_t)e*2048 + h*256 + d);
        sm[je][d] = s;
    }
    __syncthreads();
    // phase 2: Mt[d, e0+je] = sum_dp sm[je][dp]*Wv[dp*256+d], dp split by half
    float acc[8] = {0,0,0,0,0,0,0,0};
    int dp0 = hf * 128;
    #pragma unroll 4
    for (int dp = dp0; dp < dp0 + 128; ++dp){
        float wv = ldin<B>(Wv, (size_t)dp*256 + d);
        #pragma unroll
        for (int je = 0; je < 8; ++je) acc[je] += sm[je][dp] * wv;
    }
    #pragma unroll
    for (int je = 0; je < 8; ++je) ps[hf][d*8 + je] = acc[je];
    __syncthreads();
    if (t < 256){
        #pragma unroll
        for (int je = 0; je < 8; ++je){
            float v = ps[0][t*8 + je] + ps[1][t*8 + je];
            unsigned short hi = f2b(v);
            unsigned short lo = f2b(v - b2f(hi));
            int ad = waddr(t, e0 + je);
            WmH[ad] = hi; WmL[ad] = lo;
        }
    }
}
__global__ __launch_bounds__(512)
void k_prep(const void* __restrict__ values,
            const void* __restrict__ Wq, const void* __restrict__ Wk,
            const void* __restrict__ Wo, const void* __restrict__ Wv,
            unsigned short* __restrict__ WgH, unsigned short* __restrict__ WgL,
            unsigned short* __restrict__ WmH, unsigned short* __restrict__ WmL){
    __shared__ float sm[8][256];        // 8 KB
    __shared__ float ps[2][2048];       // 16 KB
    __shared__ int pc;
    bool bf = probe_bf16((const uint32_t*)values, &pc);
    if (blockIdx.x < 256){
        if (bf) gt_body<true >(Wq, Wk, WgH, WgL, blockIdx.x, ps);
        else    gt_body<false>(Wq, Wk, WgH, WgL, blockIdx.x, ps);
    } else {
        int bx = blockIdx.x - 256;
        if (bf) wosmt_body<true >(Wo, Wv, WmH, WmL, bx, sm, ps);
        else    wosmt_body<false>(Wo, Wv, WmH, WmL, bx, sm, ps);
    }
}

// ---------------- MFMA projections -> frag-order kkF / utF ------------------
// 32 rows/block: 128 key-blocks + 128 value-blocks. f32 A split to bf16 hi/lo
// in-register, 3 MFMA passes. D -> 16KB LDS staging -> linear dwordx4 copyout.
template<bool B>
__device__ void projM_body(const void* __restrict__ A,
                           const unsigned short* __restrict__ WH,
                           const unsigned short* __restrict__ WL,
                           unsigned short* __restrict__ outF,
                           int bx, bool keysHalf, unsigned short* St){
    int t = threadIdx.x, lane = t & 63, w = t >> 6;
    int l15 = t & 15, g = (t >> 4) & 3;
    int n   = bx >> 4;
    int r0n = (bx & 15) * 32;
    int r0  = n*512 + r0n;              // row in the 4096-row matrix

    f32x4 acc[2][2];
    #pragma unroll
    for (int rt = 0; rt < 2; ++rt)
        #pragma unroll
        for (int c = 0; c < 2; ++c) acc[rt][c] = (f32x4){0.f,0.f,0.f,0.f};

    s16x8 wh[3][2], wl[3][2];
    auto LDW = [&](int ks, int sl){
        #pragma unroll
        for (int c = 0; c < 2; ++c){
            size_t off = (size_t)(((w*2 + c)*8 + ks)*512 + lane*8);
            wh[sl][c] = *(const s16x8*)(WH + off);
            wl[sl][c] = *(const s16x8*)(WL + off);
        }
    };
    float4 ar[2][2][2];                 // [slot][rt][half] raw f32
    s16x8  ab[2][2];                    // [slot][rt] bf16 direct
    auto LDA = [&](int ks, int sl){
        #pragma unroll
        for (int rt = 0; rt < 2; ++rt){
            size_t idx = (size_t)(r0 + rt*16 + l15)*256 + ks*32 + g*8;
            if (B) ab[sl][rt] = *(const s16x8*)((const unsigned short*)A + idx);
            else { ar[sl][rt][0] = *(const float4*)((const float*)A + idx);
                   ar[sl][rt][1] = *(const float4*)((const float*)A + idx + 4); }
        }
    };
    LDW(0,0); LDW(1,1); LDA(0,0); LDA(1,1);

    #pragma unroll
    for (int ks = 0; ks < 8; ++ks){
        int s = ks & 1, sw = ks % 3;
        s16x8 ah[2], al[2];
        #pragma unroll
        for (int rt = 0; rt < 2; ++rt){
            if (B){
                ah[rt] = ab[s][rt];
            } else {
                union { s16x8 v; uint32_t u[4]; } H, L;
                float4 x0 = ar[s][rt][0], x1 = ar[s][rt][1];
                H.u[0] = cvtpk(x0.x, x0.y); H.u[1] = cvtpk(x0.z, x0.w);
                H.u[2] = cvtpk(x1.x, x1.y); H.u[3] = cvtpk(x1.z, x1.w);
                L.u[0] = cvtpk(x0.x - b2f_lo(H.u[0]), x0.y - b2f_hi(H.u[0]));
                L.u[1] = cvtpk(x0.z - b2f_lo(H.u[1]), x0.w - b2f_hi(H.u[1]));
                L.u[2] = cvtpk(x1.x - b2f_lo(H.u[2]), x1.y - b2f_hi(H.u[2]));
                L.u[3] = cvtpk(x1.z - b2f_lo(H.u[3]), x1.w - b2f_hi(H.u[3]));
                ah[rt] = H.v; al[rt] = L.v;
            }
        }
        if (ks + 2 < 8) LDA(ks + 2, s);     // slot just consumed
        #pragma unroll
        for (int rt = 0; rt < 2; ++rt)
            #pragma unroll
            for (int c = 0; c < 2; ++c){
                acc[rt][c] = mfma16(ah[rt], wh[sw][c], acc[rt][c]);
                if (!B) acc[rt][c] = mfma16(al[rt], wh[sw][c], acc[rt][c]);
                acc[rt][c] = mfma16(ah[rt], wl[sw][c], acc[rt][c]);
            }
        if (ks + 2 < 8) LDW(ks + 2, (ks + 2) % 3);
    }

    // D scatter to St in frag-image order.
    #pragma unroll
    for (int rt = 0; rt < 2; ++rt){
        #pragma unroll
        for (int c = 0; c < 2; ++c){
            #pragma unroll
            for (int j = 0; j < 4; ++j){
                int rloc = g*4 + j;              // 0..15 within rt-tile
                int col  = (w*2 + c)*16 + l15;
                int idx;
                if (keysHalf)
                    idx = rt*4096 + ((col >> 5) << 9)
                        + ((rloc | (((col >> 3) & 3) << 4)) << 3) + (col & 7);
                else {
                    int kl = rt*16 + rloc;       // key local 0..31
                    idx = ((col >> 4) << 9)
                        + (((col & 15) | ((kl >> 3) << 4)) << 3) + (kl & 7);
                }
                St[idx] = f2b(acc[rt][c][j]);
            }
        }
    }
    __syncthreads();

    // copyout: 8192 elems = 512 thr x 16 (two dwordx4 each)
    #pragma unroll
    for (int h = 0; h < 2; ++h){
        int s8 = t*8 + h*4096;
        if (keysHalf){
            size_t base = (size_t)n*PAN + (size_t)((r0n >> 4)*8)*512;
            *(s16x8*)(outF + base + s8) = *(const s16x8*)(St + s8);
        } else {
            int ks2 = r0n >> 5;
            int fl = s8 >> 9, off = s8 & 511;
            *(s16x8*)(outF + (size_t)n*PAN + (size_t)((fl*16 + ks2)*512 + off))
                = *(const s16x8*)(St + s8);
        }
    }
}
__global__ __launch_bounds__(512)
void k_projM(const void* __restrict__ keys, const void* __restrict__ values,
             const unsigned short* __restrict__ WgH, const unsigned short* __restrict__ WgL,
             const unsigned short* __restrict__ WmH, const unsigned short* __restrict__ WmL,
             unsigned short* __restrict__ kkF, unsigned short* __restrict__ utF){
    __shared__ unsigned short St[8192];   // 16 KB staging
    __shared__ int pc;
    bool bf = probe_bf16((const uint32_t*)values, &pc);
    int bx = blockIdx.x;
    bool keysHalf = (bx < 128);
    int bxl = bx & 127;
    if (keysHalf){
        if (bf) projM_body<true >(keys, WgH, WgL, kkF, bxl, true, St);
        else    projM_body<false>(keys, WgH, WgL, kkF, bxl, true, St);
    } else {
        if (bf) projM_body<true >(values, WmH, WmL, utF, bxl, false, St);
        else    projM_body<false>(values, WmH, WmL, utF, bxl, false, St);
    }
}

// ---------------- fused: MFMA QK^T -> in-reg softmax -> MFMA PV -> +bo -------
// (R5 configuration: BMR=32, 512 thr / 8 waves, 2 blocks/CU, 51 KB LDS)
template<bool B>
__device__ void fused_body(const void* __restrict__ query,
                           const unsigned short* __restrict__ kkF,
                           const unsigned short* __restrict__ utF,
                           const int* __restrict__ mask,
                           const void* __restrict__ bo,
                           void* __restrict__ out,
                           unsigned short* Qs, unsigned short* Pf,
                           float* redM, float* redS){
    int bid = blockIdx.x;
    int n   = bid & 7;                 // all 64 blocks of a batch on one XCD
    int r0  = (bid >> 3) * BMR;
    int t   = threadIdx.x;
    int l15 = t & 15;
    int g   = (t >> 4) & 3;            // 16-lane group within wave
    int w   = t >> 6;                  // wave 0..7
    int lane = t & 63;

    const unsigned short* Kn = kkF + (size_t)n*PAN;
    const unsigned short* Un = utF + (size_t)n*PAN;
    const int* mn = mask + n*KL;

    // ---- phase 0: stage Q tile to LDS as bf16, XOR-swizzled ----
    {
        int row = t >> 4;              // 0..31
        int c0  = (t & 15) * 16;
        int sw  = (row & 7) << 3;      // 8-elem (16B) granularity
        size_t qoff = (size_t)n*RPN*ED + (size_t)(r0 + row)*ED + c0;
        if (B){
            const unsigned short* qp = (const unsigned short*)query + qoff;
            s16x8 v0 = *(const s16x8*)(qp);
            s16x8 v1 = *(const s16x8*)(qp + 8);
            *(s16x8*)&Qs[(row*ED + c0    ) ^ sw] = v0;
            *(s16x8*)&Qs[(row*ED + c0 + 8) ^ sw] = v1;
        } else {
            const float* qp = (const float*)query + qoff;
            float4 x0 = *(const float4*)(qp);
            float4 x1 = *(const float4*)(qp + 4);
            float4 x2 = *(const float4*)(qp + 8);
            float4 x3 = *(const float4*)(qp + 12);
            union { s16x8 v; uint32_t u[4]; } pk;
            pk.u[0] = cvtpk(x0.x,x0.y); pk.u[1] = cvtpk(x0.z,x0.w);
            pk.u[2] = cvtpk(x1.x,x1.y); pk.u[3] = cvtpk(x1.z,x1.w);
            *(s16x8*)&Qs[(row*ED + c0    ) ^ sw] = pk.v;
            pk.u[0] = cvtpk(x2.x,x2.y); pk.u[1] = cvtpk(x2.z,x2.w);
            pk.u[2] = cvtpk(x3.x,x3.y); pk.u[3] = cvtpk(x3.z,x3.w);
            *(s16x8*)&Qs[(row*ED + c0 + 8) ^ sw] = pk.v;
        }
    }
    __syncthreads();

    int asw = (l15 & 7) << 3;

    // ---- GEMM1: scores S[row=rt*16+g*4+j][key=w*64+c*16+l15] in regs ----
    float p[2][4][4];
    {
        f32x4 acc1[2][4];
        #pragma unroll
        for (int rt = 0; rt < 2; ++rt)
            #pragma unroll
            for (int c = 0; c < 4; ++c) acc1[rt][c] = (f32x4){0.f,0.f,0.f,0.f};

        const unsigned short* kb = Kn + (size_t)w*16384 + (size_t)lane*8;
        s16x8 bb[3][4];                // rotating buffer, 2 k-steps ahead
        auto LDK = [&](int KS, int SL){
            #pragma unroll
            for (int c = 0; c < 4; ++c)
                bb[SL][c] = *(const s16x8*)(kb + (size_t)(c*8 + KS)*FRAG);
        };
        LDK(0,0); LDK(1,1);
        #pragma unroll
        for (int ks = 0; ks < 8; ++ks){
            if (ks + 2 < 8) LDK(ks + 2, (ks + 2) % 3);
            int col = ks*32 + g*8;
            s16x8 a0 = *(const s16x8*)&Qs[(( 0 + l15)*ED + col) ^ asw];
            s16x8 a1 = *(const s16x8*)&Qs[((16 + l15)*ED + col) ^ asw];
            #pragma unroll
            for (int c = 0; c < 4; ++c){
                acc1[0][c] = mfma16(a0, bb[ks % 3][c], acc1[0][c]);
                acc1[1][c] = mfma16(a1, bb[ks % 3][c], acc1[1][c]);
            }
        }
        #pragma unroll
        for (int c = 0; c < 4; ++c){
            bool zz = (mn[w*64 + c*16 + l15] == 0);
            #pragma unroll
            for (int rt = 0; rt < 2; ++rt)
                #pragma unroll
                for (int j = 0; j < 4; ++j)
                    p[rt][c][j] = zz ? -1e20f : acc1[rt][c][j] * 0.0625f;
        }
    }

    // ---- softmax: wave-local reduce + cross-wave via 1KB LDS ----
    {
        float mx[2][4];
        #pragma unroll
        for (int rt = 0; rt < 2; ++rt)
            #pragma unroll
            for (int j = 0; j < 4; ++j){
                float m0 = fmaxf(fmaxf(p[rt][0][j], p[rt][1][j]),
                                 fmaxf(p[rt][2][j], p[rt][3][j]));
                #pragma unroll
                for (int off = 1; off < 16; off <<= 1)
                    m0 = fmaxf(m0, __shfl_xor(m0, off, 16));
                mx[rt][j] = m0;
            }
        if (l15 == 0){
            #pragma unroll
            for (int rt = 0; rt < 2; ++rt)
                #pragma unroll
                for (int j = 0; j < 4; ++j)
                    redM[(rt*16 + g*4 + j)*8 + w] = mx[rt][j];
        }
        __syncthreads();
        float sm[2][4];
        #pragma unroll
        for (int rt = 0; rt < 2; ++rt)
            #pragma unroll
            for (int j = 0; j < 4; ++j){
                int row = rt*16 + g*4 + j;
                float4 a = *(const float4*)&redM[row*8];
                float4 b = *(const float4*)&redM[row*8 + 4];
                float m = fmaxf(fmaxf(fmaxf(a.x,a.y),fmaxf(a.z,a.w)),
                                fmaxf(fmaxf(b.x,b.y),fmaxf(b.z,b.w)));
                float s = 0.f;
                #pragma unroll
                for (int c = 0; c < 4; ++c){
                    p[rt][c][j] = __expf(p[rt][c][j] - m);
                    s += p[rt][c][j];
                }
                #pragma unroll
                for (int off = 1; off < 16; off <<= 1)
                    s += __shfl_xor(s, off, 16);
                sm[rt][j] = s;
            }
        if (l15 == 0){
            #pragma unroll
            for (int rt = 0; rt < 2; ++rt)
                #pragma unroll
                for (int j = 0; j < 4; ++j)
                    redS[(rt*16 + g*4 + j)*8 + w] = sm[rt][j];
        }
        __syncthreads();
        int ihi = ((l15 >> 3) << 4);
        int ilo = l15 & 7;
        #pragma unroll
        for (int rt = 0; rt < 2; ++rt){
            #pragma unroll
            for (int j = 0; j < 4; ++j){
                int row = rt*16 + g*4 + j;
                float4 a = *(const float4*)&redS[row*8];
                float4 b = *(const float4*)&redS[row*8 + 4];
                float inv = 1.0f / ((a.x+a.y+a.z+a.w) + (b.x+b.y+b.z+b.w));
                #pragma unroll
                for (int c = 0; c < 4; ++c){
                    int lp = (g*4 + j) | (((c & 1) << 5) | ihi);
                    int elem = (rt*16 + w*2 + (c >> 1))*FRAG + lp*8 + ilo;
                    Pf[elem] = f2b(p[rt][c][j] * inv);
                }
            }
        }
    }
    __syncthreads();

    // ---- GEMM2: Out[32 x 2 e-tiles] = P . u ----
    {
        f32x4 acc2[2][2];
        #pragma unroll
        for (int rt = 0; rt < 2; ++rt)
            #pragma unroll
            for (int c = 0; c < 2; ++c) acc2[rt][c] = (f32x4){0.f,0.f,0.f,0.f};

        const unsigned short* ub = Un + (size_t)(2*w)*8192 + (size_t)lane*8;
        s16x8 bu[3][2];
        auto LDU = [&](int KS, int SL){
            #pragma unroll
            for (int c = 0; c < 2; ++c)
                bu[SL][c] = *(const s16x8*)(ub + (size_t)(c*16 + KS)*FRAG);
        };
        LDU(0,0); LDU(1,1);
        #pragma unroll
        for (int ks = 0; ks < 16; ++ks){
            if (ks + 2 < 16) LDU(ks + 2, (ks + 2) % 3);
            s16x8 p0 = *(const s16x8*)&Pf[( 0 + ks)*FRAG + lane*8];
            s16x8 p1 = *(const s16x8*)&Pf[(16 + ks)*FRAG + lane*8];
            #pragma unroll
            for (int c = 0; c < 2; ++c){
                acc2[0][c] = mfma16(p0, bu[ks % 3][c], acc2[0][c]);
                acc2[1][c] = mfma16(p1, bu[ks % 3][c], acc2[1][c]);
            }
        }
        float bov[2];
        #pragma unroll
        for (int c = 0; c < 2; ++c) bov[c] = ldin<B>(bo, (2*w + c)*16 + l15);
        #pragma unroll
        for (int rt = 0; rt < 2; ++rt){
            #pragma unroll
            for (int j = 0; j < 4; ++j){
                int row = rt*16 + g*4 + j;
                #pragma unroll
                for (int c = 0; c < 2; ++c){
                    int e = (2*w + c)*16 + l15;
                    float val = acc2[rt][c][j] + bov[c];
                    size_t oidx = (size_t)n*RPN*ED + (size_t)(r0 + row)*ED + e;
                    if (B) ((unsigned short*)out)[oidx] = f2b(val);
                    else   ((float*)out)[oidx] = val;
                }
            }
        }
    }
}

__global__ __launch_bounds__(512, 4)
void k_fused4(const void* __restrict__ values, const void* __restrict__ query,
              const unsigned short* __restrict__ kkF,
              const unsigned short* __restrict__ utF,
              const int* __restrict__ mask, const void* __restrict__ bo,
              void* __restrict__ out){
    __shared__ unsigned short Qs[BMR*ED];   // 16 KB
    __shared__ unsigned short Pf[32*FRAG];  // 32 KB (A-frag-order P)
    __shared__ float redM[BMR*8];           // 1 KB
    __shared__ float redS[BMR*8];           // 1 KB   (total ~51 KB -> 2 blk/CU)
    __shared__ int pc;
    bool bf = probe_bf16((const uint32_t*)values, &pc);
    if (bf) fused_body<true >(query, kkF, utF, mask, bo, out, Qs, Pf, redM, redS);
    else    fused_body<false>(query, kkF, utF, mask, bo, out, Qs, Pf, redM, redS);
}

// ---------------- launch ----------------
extern "C" void kernel_launch(void* const* d_in, const int* in_sizes, int n_in,
                              void* d_out, int out_size, void* d_ws, size_t ws_size,
                              hipStream_t stream){
    const void* values = d_in[0];
    const void* keys   = d_in[1];
    const void* query  = d_in[2];
    const int*  mask   = (const int*)d_in[3];
    const void* Wv     = d_in[4];
    const void* Wk     = d_in[5];
    const void* Wq     = d_in[6];
    const void* Wo     = d_in[7];
    const void* bo     = d_in[8];

    // ws layout (u16 elems): [WgH 64Ki][WgL 64Ki][WmH 64Ki][WmL 64Ki]
    //                        [kkF 1Mi][utF 1Mi]
    unsigned short* wsu = (unsigned short*)d_ws;
    unsigned short* wgh = wsu;
    unsigned short* wgl = wsu + 65536;
    unsigned short* wmh = wsu + 131072;
    unsigned short* wml = wsu + 196608;
    unsigned short* ws_kk = wsu + 262144;
    unsigned short* ws_u  = ws_kk + (size_t)NB*PAN;

    k_prep  <<< 288, 512, 0, stream>>>(values, Wq, Wk, Wo, Wv, wgh, wgl, wmh, wml);
    k_projM <<< 256, 512, 0, stream>>>(keys, values, wgh, wgl, wmh, wml, ws_kk, ws_u);
    k_fused4<<< 512, 512, 0, stream>>>(values, query, ws_kk, ws_u, mask, bo, d_out);
}